// Round 4
// baseline (546.966 us; speedup 1.0000x reference)
//
#include <hip/hip_runtime.h>

#define B_SZ 1024
#define D_SZ 128
#define KTERMS 8

typedef float vfloat4 __attribute__((ext_vector_type(4)));
typedef float f32x16 __attribute__((ext_vector_type(16)));
typedef short bf16x8 __attribute__((ext_vector_type(8)));

// f32 -> bf16 (round-to-nearest-even), bit pattern in a short
__device__ inline short f2bf(float x) {
    union { float f; unsigned u; } c; c.f = x;
    unsigned u = c.u + 0x7fffu + ((c.u >> 16) & 1u);
    return (short)(u >> 16);
}

// A-operand fragment of 32x32x16 bf16 MFMA from row-major f32 matrix:
// lane holds M[r][k0..k0+7] (8 consecutive k).  r = mr*32 + (lane&31),
// k0 = ks*16 + 8*(lane>>5).
__device__ inline bf16x8 afrag(const float* M, int r, int k0) {
    const float4* p = (const float4*)(M + r * 128 + k0);
    float4 x0 = p[0], x1 = p[1];
    bf16x8 f;
    f[0] = f2bf(x0.x); f[1] = f2bf(x0.y); f[2] = f2bf(x0.z); f[3] = f2bf(x0.w);
    f[4] = f2bf(x1.x); f[5] = f2bf(x1.y); f[6] = f2bf(x1.z); f[7] = f2bf(x1.w);
    return f;
}

// B-operand fragment: lane holds M[k0+e][c], e=0..7 (c = nc*32 + (lane&31)).
// Per e the wave reads 2 rows x 128 contiguous bytes -> coalesced, L2/L3-hot.
__device__ inline bf16x8 bfrag(const float* M, int k0, int c) {
    bf16x8 f;
#pragma unroll
    for (int e = 0; e < 8; ++e) f[e] = f2bf(M[(k0 + e) * 128 + c]);
    return f;
}

// One block (512 threads) per batch element.
// Phase 1: stream A0,W -> emit A1,A2 (nontemporal).
// Phase 2: comm = A0*W - W*A0 via bf16 MFMA (fp32 accum); assemble
//          Omega = h*A0 + hs*W - c3*comm  into LDS (fp32, XOR-swizzled).
//          bf16 error enters only through c3 ~ 8.3e-5 -> negligible.
// Phase 3: y = expm(Omega) y0, 8-term Taylor: 8 rounds of Omega*v,
//          one barrier per round (quarter-row dots + 2 shfl combines).
__global__ void __launch_bounds__(512, 4)
magnus_kernel(const float* __restrict__ t0p, const float* __restrict__ hp,
              const float* __restrict__ y0, const float* __restrict__ A0,
              const float* __restrict__ W, float* __restrict__ out)
{
    __shared__ __align__(16) float sOmega[D_SZ * D_SZ];  // 64 KB
    __shared__ __align__(16) float sv[2][D_SZ];          // double-buffered vector

    const int b = blockIdx.x;
    const int tid = threadIdx.x;
    const float h = hp[0];
    const float tb = t0p[b];
    const float SQ3_6 = 0.28867513459481287f;  // sqrt(3)/6
    const float t1 = tb + (0.5f - SQ3_6) * h;
    const float t2 = tb + (0.5f + SQ3_6) * h;

    const size_t moff = (size_t)b * (D_SZ * D_SZ);
    const float4* A0v = (const float4*)(A0 + moff);
    const float4* Wv  = (const float4*)(W + moff);
    vfloat4* o1 = (vfloat4*)(out + (size_t)B_SZ * D_SZ + moff);
    vfloat4* o2 = (vfloat4*)(out + (size_t)B_SZ * D_SZ
                                 + (size_t)B_SZ * D_SZ * D_SZ + moff);

    // ---- Phase 1: stream A0, W once; emit A1, A2 (nontemporal) ----
#pragma unroll 8
    for (int it = 0; it < 8; ++it) {
        int i = it * 512 + tid;  // float4 chunk 0..4095
        float4 a = A0v[i];
        float4 w = Wv[i];
        vfloat4 p1, p2;
        p1.x = fmaf(t1, w.x, a.x); p1.y = fmaf(t1, w.y, a.y);
        p1.z = fmaf(t1, w.z, a.z); p1.w = fmaf(t1, w.w, a.w);
        p2.x = fmaf(t2, w.x, a.x); p2.y = fmaf(t2, w.y, a.y);
        p2.z = fmaf(t2, w.z, a.z); p2.w = fmaf(t2, w.w, a.w);
        __builtin_nontemporal_store(p1, o1 + i);
        __builtin_nontemporal_store(p2, o2 + i);
    }

    // ---- Phase 2: MFMA commutator + Omega assembly into LDS ----
    const int l  = tid & 63;       // lane
    const int w  = tid >> 6;       // wave 0..7
    const int lh = l >> 5;         // half (k-offset select)
    const int lc = l & 31;

    const float* Ag = A0 + moff;
    const float* Wg = W  + moff;

    const float hs = h * (tb + 0.5f * h);         // h * s
    const float c3 = h * h * h * (1.0f / 12.0f);  // h^3 / 12

#pragma unroll
    for (int t = 0; t < 2; ++t) {
        const int tile = w * 2 + t;        // 0..15
        const int mr = tile >> 2, nc = tile & 3;
        const int ra = mr * 32 + lc;       // A-operand row
        const int cb = nc * 32 + lc;       // B-operand col

        f32x16 acc1 = {};  // A0 * W
#pragma unroll
        for (int ks = 0; ks < 8; ++ks) {
            int k0 = ks * 16 + 8 * lh;
            bf16x8 aA = afrag(Ag, ra, k0);
            bf16x8 bW = bfrag(Wg, k0, cb);
            acc1 = __builtin_amdgcn_mfma_f32_32x32x16_bf16(aA, bW, acc1, 0, 0, 0);
        }
        f32x16 acc2 = {};  // W * A0
#pragma unroll
        for (int ks = 0; ks < 8; ++ks) {
            int k0 = ks * 16 + 8 * lh;
            bf16x8 aW = afrag(Wg, ra, k0);
            bf16x8 bA = bfrag(Ag, k0, cb);
            acc2 = __builtin_amdgcn_mfma_f32_32x32x16_bf16(aW, bA, acc2, 0, 0, 0);
        }
        // C layout (m74/m101): col = lane&31, row = (reg&3)+8*(reg>>2)+4*(lane>>5)
#pragma unroll
        for (int reg = 0; reg < 16; ++reg) {
            int grow = mr * 32 + (reg & 3) + 8 * (reg >> 2) + 4 * lh;
            int gcol = nc * 32 + lc;
            float a0v = Ag[grow * 128 + gcol];
            float wv  = Wg[grow * 128 + gcol];
            float om = fmaf(h, a0v, fmaf(hs, wv, -c3 * (acc1[reg] - acc2[reg])));
            // XOR-swizzle cols (bits 2..4) for bank-balanced b128 reads later
            sOmega[grow * 128 + (gcol ^ ((grow & 7) << 2))] = om;
        }
    }

    // ---- Phase 3: Taylor chain, one barrier per term ----
    // thread -> (row, quarter): row = 16*w + (l&15), quarter = l>>4
    const int q    = l >> 4;
    const int prow = w * 16 + (l & 15);
    float yacc = 0.0f;
    if (l < 16) {
        float v = y0[(size_t)b * D_SZ + prow];
        sv[0][prow] = v;
        yacc = v;
    }
    __syncthreads();  // covers Omega writes + sv[0] init

    const float* orow = sOmega + prow * 128;
    const int sw = (prow & 7) << 2;
#pragma unroll
    for (int k = 1; k <= KTERMS; ++k) {
        const float* vin = sv[(k - 1) & 1];
        float s0 = 0.f, s1 = 0.f, s2 = 0.f, s3 = 0.f;
#pragma unroll
        for (int c = 0; c < 8; ++c) {
            int colb = q * 32 + 4 * c;
            vfloat4 ov = *(const vfloat4*)(orow + (colb ^ sw));
            vfloat4 vv = *(const vfloat4*)(vin + colb);
            s0 = fmaf(ov.x, vv.x, s0);
            s1 = fmaf(ov.y, vv.y, s1);
            s2 = fmaf(ov.z, vv.z, s2);
            s3 = fmaf(ov.w, vv.w, s3);
        }
        float a = (s0 + s1) + (s2 + s3);
        a += __shfl_xor(a, 16);   // combine quarters
        a += __shfl_xor(a, 32);
        if (l < 16) {
            float wn = a * (1.0f / (float)k);   // folds to constant
            yacc += wn;
            sv[k & 1][prow] = wn;
        }
        __syncthreads();
    }

    if (l < 16) {
        out[(size_t)b * D_SZ + prow] = yacc;
    }
}

extern "C" void kernel_launch(void* const* d_in, const int* in_sizes, int n_in,
                              void* d_out, int out_size, void* d_ws, size_t ws_size,
                              hipStream_t stream) {
    const float* t0 = (const float*)d_in[0];
    const float* h  = (const float*)d_in[1];
    const float* y0 = (const float*)d_in[2];
    const float* A0 = (const float*)d_in[3];
    const float* W  = (const float*)d_in[4];
    float* out = (float*)d_out;
    magnus_kernel<<<B_SZ, 512, 0, stream>>>(t0, h, y0, A0, W, out);
}

// Round 5
// 257.201 us; speedup vs baseline: 2.1266x; 2.1266x over previous
//
#include <hip/hip_runtime.h>

#define B_SZ 1024
#define D_SZ 128
#define KTERMS 8
#define RSTRIDE 68   // uints per row: 64 data + 4 pad (272 B) -> bank-balanced b128 reads

typedef float vfloat4 __attribute__((ext_vector_type(4)));

__device__ inline float bflo(unsigned u) { return __uint_as_float(u << 16); }
__device__ inline float bfhi(unsigned u) { return __uint_as_float(u & 0xffff0000u); }

// 64-elem dot: bf16 row half from LDS (8 x ds_read_b128) x fp32 vector (broadcast reads)
__device__ inline float dotlds(const unsigned* rq, const float* v) {
    float a0 = 0.f, a1 = 0.f, a2 = 0.f, a3 = 0.f;
#pragma unroll
    for (int j = 0; j < 8; ++j) {
        uint4 qq = *(const uint4*)(rq + 4 * j);
        vfloat4 v0 = *(const vfloat4*)(v + 8 * j);
        vfloat4 v1 = *(const vfloat4*)(v + 8 * j + 4);
        a0 = fmaf(bflo(qq.x), v0.x, a0);
        a1 = fmaf(bfhi(qq.x), v0.y, a1);
        a2 = fmaf(bflo(qq.y), v0.z, a2);
        a3 = fmaf(bfhi(qq.y), v0.w, a3);
        a0 = fmaf(bflo(qq.z), v1.x, a0);
        a1 = fmaf(bfhi(qq.z), v1.y, a1);
        a2 = fmaf(bflo(qq.w), v1.z, a2);
        a3 = fmaf(bfhi(qq.w), v1.w, a3);
    }
    return (a0 + a1) + (a2 + a3);
}

// One block (512 threads) per batch element.
// Phase 1: stream A0,W once; emit A1,A2 (nontemporal) AND stage bf16(A0), bf16(W)
//          into LDS (free: data already in registers; v_cvt_pk_bf16_f32 packs).
// Phase 3: r3-proven 2-round Taylor: per term
//          u1=A0 v | u2=W v,  then  u3=A0 u2 | u4=W u1,
//          wn = h*u1 + hs*u2 - c3*(u3-u4);  rows read from LDS bf16.
__global__ void __launch_bounds__(512, 4)
magnus_kernel(const float* __restrict__ t0p, const float* __restrict__ hp,
              const float* __restrict__ y0, const float* __restrict__ A0,
              const float* __restrict__ W, float* __restrict__ out)
{
    __shared__ __align__(16) unsigned sA[D_SZ * RSTRIDE];  // 34,816 B (bf16 pairs)
    __shared__ __align__(16) unsigned sW[D_SZ * RSTRIDE];  // 34,816 B
    __shared__ __align__(16) float sv[D_SZ];
    __shared__ __align__(16) float su1[D_SZ];
    __shared__ __align__(16) float su2[D_SZ];
    __shared__ __align__(16) float su3[D_SZ];
    __shared__ __align__(16) float su4[D_SZ];

    const int b = blockIdx.x;
    const int tid = threadIdx.x;
    const float h = hp[0];
    const float tb = t0p[b];
    const float SQ3_6 = 0.28867513459481287f;  // sqrt(3)/6
    const float t1 = tb + (0.5f - SQ3_6) * h;
    const float t2 = tb + (0.5f + SQ3_6) * h;

    const size_t moff = (size_t)b * (D_SZ * D_SZ);
    const float4* A0v = (const float4*)(A0 + moff);
    const float4* Wv  = (const float4*)(W + moff);
    vfloat4* o1 = (vfloat4*)(out + (size_t)B_SZ * D_SZ + moff);
    vfloat4* o2 = (vfloat4*)(out + (size_t)B_SZ * D_SZ
                                 + (size_t)B_SZ * D_SZ * D_SZ + moff);

    // ---- Phase 1: stream + emit A1/A2 + stage bf16 rows to LDS ----
#pragma unroll 8
    for (int it = 0; it < 8; ++it) {
        int i = it * 512 + tid;  // float4 chunk 0..4095
        float4 a = A0v[i];
        float4 w = Wv[i];
        vfloat4 p1, p2;
        p1.x = fmaf(t1, w.x, a.x); p1.y = fmaf(t1, w.y, a.y);
        p1.z = fmaf(t1, w.z, a.z); p1.w = fmaf(t1, w.w, a.w);
        p2.x = fmaf(t2, w.x, a.x); p2.y = fmaf(t2, w.y, a.y);
        p2.z = fmaf(t2, w.z, a.z); p2.w = fmaf(t2, w.w, a.w);
        __builtin_nontemporal_store(p1, o1 + i);
        __builtin_nontemporal_store(p2, o2 + i);

        // stage bf16 (RNE pack, 2 elems/instr).  low 16 bits = src0 (even col).
        unsigned pa0, pa1, pw0, pw1;
        asm("v_cvt_pk_bf16_f32 %0, %1, %2" : "=v"(pa0) : "v"(a.x), "v"(a.y));
        asm("v_cvt_pk_bf16_f32 %0, %1, %2" : "=v"(pa1) : "v"(a.z), "v"(a.w));
        asm("v_cvt_pk_bf16_f32 %0, %1, %2" : "=v"(pw0) : "v"(w.x), "v"(w.y));
        asm("v_cvt_pk_bf16_f32 %0, %1, %2" : "=v"(pw1) : "v"(w.z), "v"(w.w));
        int r = i >> 5;            // row 0..127
        int p = (2 * i) & 63;      // uint (elem-pair) index within row, even
        *(uint2*)(&sA[r * RSTRIDE + p]) = make_uint2(pa0, pa1);
        *(uint2*)(&sW[r * RSTRIDE + p]) = make_uint2(pw0, pw1);
    }

    // ---- Phase 3 setup: thread -> (grp, row, half) ----
    const int grp  = tid >> 8;           // 0 = A0 rows, 1 = W rows
    const int t8   = tid & 255;
    const int half = (t8 >> 5) & 1;      // lane bit 5 -> shfl_xor(32) partner
    const int row  = (t8 & 31) + ((t8 >> 6) << 5);
    const unsigned* rq = (grp ? sW : sA) + row * RSTRIDE + half * 32;

    float yacc = 0.0f;
    if (tid < D_SZ) {
        float v = y0[(size_t)b * D_SZ + tid];
        sv[tid] = v;
        yacc = v;
    }
    __syncthreads();  // covers bf16 staging + sv init

    const float hs = h * (tb + 0.5f * h);           // h * s
    const float c3 = h * h * h * (1.0f / 12.0f);    // h^3 / 12

#pragma unroll
    for (int k = 1; k <= KTERMS; ++k) {
        // Round A: u1 = A0 v (grp 0) | u2 = W v (grp 1)
        float a = dotlds(rq, sv + half * 64);
        a += __shfl_xor(a, 32);
        if (!half) { if (grp == 0) su1[row] = a; else su2[row] = a; }
        __syncthreads();
        // Round B: u3 = A0 u2 (grp 0) | u4 = W u1 (grp 1)
        const float* vb = grp ? su1 : su2;
        float c = dotlds(rq, vb + half * 64);
        c += __shfl_xor(c, 32);
        if (!half) { if (grp == 0) su3[row] = c; else su4[row] = c; }
        __syncthreads();
        if (tid < D_SZ) {
            float wn = h * su1[tid] + hs * su2[tid] - c3 * (su3[tid] - su4[tid]);
            wn *= (1.0f / (float)k);     // folds to constant (unrolled)
            yacc += wn;
            sv[tid] = wn;
        }
        __syncthreads();
    }

    if (tid < D_SZ) {
        out[(size_t)b * D_SZ + tid] = yacc;
    }
}

extern "C" void kernel_launch(void* const* d_in, const int* in_sizes, int n_in,
                              void* d_out, int out_size, void* d_ws, size_t ws_size,
                              hipStream_t stream) {
    const float* t0 = (const float*)d_in[0];
    const float* h  = (const float*)d_in[1];
    const float* y0 = (const float*)d_in[2];
    const float* A0 = (const float*)d_in[3];
    const float* W  = (const float*)d_in[4];
    float* out = (float*)d_out;
    magnus_kernel<<<B_SZ, 512, 0, stream>>>(t0, h, y0, A0, W, out);
}